// Round 16
// baseline (48.864 us; speedup 1.0000x reference)
//
#include <hip/hip_runtime.h>
#include <stdint.h>

// TransConv fused form, round 16 = round 14 (best: 35.4us)
//  + v_cvt_pk_bf16_f32 epilogue pack (1 inst vs ~6 per bf16 pair)
//  + residual h_prev in registers (deletes 32 ds_read_u16/thread/layer;
//    fp32 residual, absmax improves to ~0.035 per r13/r15)
// WITHOUT r15's global_load_lds staging (counter-diagnosed as the regression:
// FETCH 4x / WRITE 2x blow-up from scattered 16B async loads).
// Validated algebra (r2-r15, absmax <= 0.0625):
//   h <- relu(LN((h @ Wv_mean + bvm + h)/2)),  fc0: h0 = relu(LN(x@W0+b)).

typedef unsigned short u16;
typedef unsigned int u32;
typedef __attribute__((ext_vector_type(8))) short bf16x8;
typedef __attribute__((ext_vector_type(8))) unsigned short u16x8;
typedef __attribute__((ext_vector_type(4))) float f32x4;

#define APAD 264   // As row stride (u16)

static __device__ __forceinline__ float bf2f(u16 u) {
  union { u32 i; float f; } c; c.i = ((u32)u) << 16; return c.f;
}
static __device__ __forceinline__ u16 f2bf(float f) {
  union { float ff; u32 i; } c; c.ff = f;
  u32 x = c.i;
  x += 0x7fffu + ((x >> 16) & 1u);   // RNE
  return (u16)(x >> 16);
}
static __device__ __forceinline__ bf16x8 as_bf(u16x8 v) {
  union { u16x8 a; bf16x8 b; } c; c.a = v; return c.b;
}
// quad_perm DPP lane exchanges (pure VALU, no LDS/lgkm):
static __device__ __forceinline__ float dpp_x1(float v) {   // lane ^ 1
  return __int_as_float(__builtin_amdgcn_mov_dpp(__float_as_int(v), 0xB1, 0xF, 0xF, true));
}
static __device__ __forceinline__ float dpp_x2(float v) {   // lane ^ 2
  return __int_as_float(__builtin_amdgcn_mov_dpp(__float_as_int(v), 0x4E, 0xF, 0xF, true));
}
// packed bf16 pair via HW cvt (RNE), src0 -> lo, src1 -> hi:
static __device__ __forceinline__ u32 pk_bf16(float lo, float hi) {
  u32 r;
  asm("v_cvt_pk_bf16_f32 %0, %1, %2" : "=v"(r) : "v"(lo), "v"(hi));
  return r;
}

// ---------------------------------------------------------------------------
// Prep (unchanged since r5). grid 33 x 256.
//  bid 0..31 : W2{L}[kt][d][q][e] = bf16(mean_h wv{L}[kt*32+q*8+e][h*256+d])
//  bid 32    : w0T[d][k] = bf16(fc0_w[k][d]);  bvm{L}[d] = mean_h bv{L}
// ---------------------------------------------------------------------------
__global__ __launch_bounds__(256) void k_prep(
    const float* __restrict__ fc0_w,
    const float* __restrict__ wv0, const float* __restrict__ bv0,
    const float* __restrict__ wv1, const float* __restrict__ bv1,
    u16* __restrict__ w0T,
    u16* __restrict__ w2_0, float* __restrict__ bvm0,
    u16* __restrict__ w2_1, float* __restrict__ bvm1)
{
  const int bid = blockIdx.x, tid = threadIdx.x;
  if (bid < 32) {
    __shared__ u16 t[64][72];
    const int L  = bid >> 4;
    const int ti = (bid >> 2) & 3;
    const int tj = bid & 3;
    const float* wv = L ? wv1 : wv0;
    u16* W2 = L ? w2_1 : w2_0;
    const int cl = tid >> 2, dq = tid & 3;
    #pragma unroll
    for (int e = 0; e < 16; e++) {
      const int dl = dq * 16 + e;
      const float* p = wv + (size_t)(ti * 64 + cl) * 1024 + tj * 64 + dl;
      t[cl][dl] = f2bf(0.25f * (p[0] + p[256] + p[512] + p[768]));
    }
    __syncthreads();
    const int dl = tid >> 2, cq = tid & 3;
    u16x8 v0, v1;
    #pragma unroll
    for (int e = 0; e < 8; e++) { v0[e] = t[cq * 16 + e][dl]; v1[e] = t[cq * 16 + 8 + e][dl]; }
    const int kt = ti * 2 + (cq >> 1);
    const int q0 = (cq & 1) * 2;
    const int d  = tj * 64 + dl;
    u16* dst = W2 + kt * 8192 + d * 32 + q0 * 8;
    *(u16x8*)dst = v0;
    *(u16x8*)(dst + 8) = v1;
  } else {
    const int d = tid;
    u16x8 r0, r1;
    #pragma unroll
    for (int k = 0; k < 8; k++) {
      r0[k] = f2bf(fc0_w[k * 256 + d]);
      r1[k] = f2bf(fc0_w[(k + 8) * 256 + d]);
    }
    *(u16x8*)(w0T + d * 16) = r0;
    *(u16x8*)(w0T + d * 16 + 8) = r1;
    float t0 = 0.f, t1 = 0.f;
    #pragma unroll
    for (int h = 0; h < 4; h++) { t0 += bv0[h * 256 + d]; t1 += bv1[h * 256 + d]; }
    bvm0[d] = 0.25f * t0;
    bvm1[d] = 0.25f * t1;
  }
}

// ---------------------------------------------------------------------------
// Mega kernel: 512 blocks x 512 threads (8 waves: 2 row-groups x 4 col-
// stripes), 64 rows/block, 2 blocks/CU. Weight chunks K=32 (16KB) dbuf,
// reg-staged, XOR-swizzled. Epilogue: quad-DPP + LDS float2 partials +
// cvt_pk store; residual in registers.
// C/D map (HW-verified m89/m91): row = rbase + i*16 + fq*4 + r,
//                                col = wc*64 + j*16 + fr.
// Bs swizzle: slot' = slot ^ ((row>>1)&3); read kcB = (fq^((fr>>1)&3))<<3.
// ---------------------------------------------------------------------------
__global__ __launch_bounds__(512, 4) void k_mega(
    const float* __restrict__ x,
    const u16* __restrict__ w0T, const float* __restrict__ fc0_b,
    const float* __restrict__ ln0w, const float* __restrict__ ln0b,
    const u16* __restrict__ w2_0, const float* __restrict__ bvm0,
    const float* __restrict__ ln1w, const float* __restrict__ ln1b,
    const u16* __restrict__ w2_1, const float* __restrict__ bvm1,
    const float* __restrict__ ln2w, const float* __restrict__ ln2b,
    float* __restrict__ out)
{
  __shared__ u16 As[64 * APAD];        // 33.8 KB: the h tile
  __shared__ u16 Bs[2][8192];          // 32 KB: K=32 weight chunk double-buffer
  __shared__ float2 part[64][17];      // 8.7 KB
  __shared__ float stats[64][2];       // 0.5 KB            -> 75.8 KB total

  const int tid  = threadIdx.x;
  const int lane = tid & 63;
  const int w    = tid >> 6;        // 0..7
  const int wr   = w >> 2;          // row-group (0..1), 32 rows each
  const int wc   = w & 3;           // col-stripe (0..3), 64 cols each
  const int fr   = lane & 15;
  const int fq   = lane >> 4;
  const int kc   = fq << 3;
  const int kcB  = (fq ^ ((fr >> 1) & 3)) << 3;   // swizzled B chunk offset
  const int m0   = blockIdx.x * 64;
  const int rbase = wr * 32;
  const int qidx = wc * 4 + (fr >> 2);            // partial slot
  // swizzled staging dest (logical elem tid*8: row=tid>>2, slot=tid&3)
  const int swdst = ((tid >> 2) << 5) | (((tid & 3) ^ ((tid >> 3) & 3)) << 3);

  f32x4 acc[2][4];
  float hprev[2][4][4];
  #pragma unroll
  for (int i = 0; i < 2; i++)
    #pragma unroll
    for (int j = 0; j < 4; j++)
      acc[i][j] = f32x4{0.f, 0.f, 0.f, 0.f};

  // ---- Phase 0 MFMA: fc0, K=16 zero-padded to 32, operands from global ----
  {
    bf16x8 af[2], bg[4];
    if (kc < 16) {
      #pragma unroll
      for (int i = 0; i < 2; i++) {
        const float* xp = x + (size_t)(m0 + rbase + i * 16 + fr) * 16 + kc;
        const f32x4 lo = *(const f32x4*)xp;
        const f32x4 hi = *(const f32x4*)(xp + 4);
        u16x8 v;
        #pragma unroll
        for (int e = 0; e < 4; e++) { v[e] = f2bf(lo[e]); v[4 + e] = f2bf(hi[e]); }
        af[i] = as_bf(v);
      }
      #pragma unroll
      for (int j = 0; j < 4; j++)
        bg[j] = as_bf(*(const u16x8*)(w0T + (wc * 64 + j * 16 + fr) * 16 + kc));
    } else {
      const u16x8 z = {0,0,0,0,0,0,0,0};
      #pragma unroll
      for (int i = 0; i < 2; i++) af[i] = as_bf(z);
      #pragma unroll
      for (int j = 0; j < 4; j++) bg[j] = as_bf(z);
    }
    #pragma unroll
    for (int i = 0; i < 2; i++)
      #pragma unroll
      for (int j = 0; j < 4; j++)
        acc[i][j] = __builtin_amdgcn_mfma_f32_16x16x32_bf16(af[i], bg[j], acc[i][j], 0, 0, 0);
  }

  // ---- Phase 0 epilogue: +fc0_b, row-LN(ln0), relu -> As + hprev ----
  {
    float vb[4], vw[4], vl[4];
    #pragma unroll
    for (int j = 0; j < 4; j++) {
      const int c = wc * 64 + j * 16 + fr;
      vb[j] = fc0_b[c]; vw[j] = ln0w[c]; vl[j] = ln0b[c];
    }
    #pragma unroll
    for (int i = 0; i < 2; i++)
      #pragma unroll
      for (int r = 0; r < 4; r++) {
        const int row = rbase + i * 16 + fq * 4 + r;
        float s = 0.f, ss = 0.f;
        #pragma unroll
        for (int j = 0; j < 4; j++) {
          const float xv = acc[i][j][r] + vb[j];
          acc[i][j][r] = xv;
          s += xv; ss += xv * xv;
        }
        s += dpp_x1(s);  ss += dpp_x1(ss);
        s += dpp_x2(s);  ss += dpp_x2(ss);
        if ((fr & 3) == 0) part[row][qidx] = float2{s, ss};
      }
    __syncthreads();
    if (tid < 64) {
      float s = 0.f, ss = 0.f;
      #pragma unroll
      for (int k = 0; k < 16; k++) { const float2 v = part[tid][k]; s += v.x; ss += v.y; }
      const float mean = s * (1.0f / 256.0f);
      const float var  = ss * (1.0f / 256.0f) - mean * mean;
      stats[tid][0] = mean;
      stats[tid][1] = rsqrtf(var + 1e-5f);
    }
    __syncthreads();
    #pragma unroll
    for (int i = 0; i < 2; i++)
      #pragma unroll
      for (int r = 0; r < 4; r++) {
        const int row = rbase + i * 16 + fq * 4 + r;
        const float mean = stats[row][0], rstd = stats[row][1];
        #pragma unroll
        for (int j = 0; j < 4; j++) {
          const int col = wc * 64 + j * 16 + fr;
          const float y = fmaxf((acc[i][j][r] - mean) * rstd * vw[j] + vl[j], 0.f);
          hprev[i][j][r] = y;
          const float yp = dpp_x1(y);
          if ((fr & 1) == 0)
            *(u32*)&As[row * APAD + col] = pk_bf16(y, yp);
        }
      }
    __syncthreads();
  }

  // ---- Phases 1 & 2: h <- relu(LN((h @ W + bvm + h)/2)) ----
  #pragma unroll 1
  for (int p = 0; p < 2; p++) {
    const u16* W2 = p ? w2_1 : w2_0;
    const float* bvp = p ? bvm1 : bvm0;
    const float* lw  = p ? ln2w : ln1w;
    const float* lb  = p ? ln2b : ln1b;

    #pragma unroll
    for (int i = 0; i < 2; i++)
      #pragma unroll
      for (int j = 0; j < 4; j++)
        acc[i][j] = f32x4{0.f, 0.f, 0.f, 0.f};

    // LDS-staged K-loop: 8 chunks of K=32 (8192 u16), dbuf, swizzled
    u16x8 s0 = *(const u16x8*)(W2 + tid * 8);
    u16x8 s1 = *(const u16x8*)(W2 + 4096 + tid * 8);
    *(u16x8*)(&Bs[0][swdst]) = s0;
    *(u16x8*)(&Bs[0][4096 + swdst]) = s1;

    #pragma unroll
    for (int c = 0; c < 8; c++) {
      if (c < 7) {                       // issue next chunk's global loads
        s0 = *(const u16x8*)(W2 + (c + 1) * 8192 + tid * 8);
        s1 = *(const u16x8*)(W2 + (c + 1) * 8192 + 4096 + tid * 8);
      }
      __syncthreads();                   // buf[c&1] writes visible
      const u16* bbase = &Bs[c & 1][0];
      bf16x8 a[2], b[4];
      #pragma unroll
      for (int i = 0; i < 2; i++)
        a[i] = *(const bf16x8*)(As + (rbase + i * 16 + fr) * APAD + c * 32 + kc);
      #pragma unroll
      for (int j = 0; j < 4; j++)
        b[j] = *(const bf16x8*)(bbase + (wc * 64 + j * 16 + fr) * 32 + kcB);
      #pragma unroll
      for (int i = 0; i < 2; i++)
        #pragma unroll
        for (int j = 0; j < 4; j++)
          acc[i][j] = __builtin_amdgcn_mfma_f32_16x16x32_bf16(a[i], b[j], acc[i][j], 0, 0, 0);
      if (c < 7) {                       // write next chunk into other buffer
        *(u16x8*)(&Bs[(c + 1) & 1][swdst]) = s0;
        *(u16x8*)(&Bs[(c + 1) & 1][4096 + swdst]) = s1;
      }
    }

    // epilogue: xv = (C + bvm + h_prev)/2, row-LN via DPP+LDS partials
    float vb[4], vw[4], vl[4];
    #pragma unroll
    for (int j = 0; j < 4; j++) {
      const int c = wc * 64 + j * 16 + fr;
      vb[j] = bvp[c]; vw[j] = lw[c]; vl[j] = lb[c];
    }
    #pragma unroll
    for (int i = 0; i < 2; i++)
      #pragma unroll
      for (int r = 0; r < 4; r++) {
        const int row = rbase + i * 16 + fq * 4 + r;
        float s = 0.f, ss = 0.f;
        #pragma unroll
        for (int j = 0; j < 4; j++) {
          const float xv = (acc[i][j][r] + vb[j] + hprev[i][j][r]) * 0.5f;
          acc[i][j][r] = xv;
          s += xv; ss += xv * xv;
        }
        s += dpp_x1(s);  ss += dpp_x1(ss);
        s += dpp_x2(s);  ss += dpp_x2(ss);
        if ((fr & 3) == 0) part[row][qidx] = float2{s, ss};
      }
    __syncthreads();
    if (tid < 64) {
      float s = 0.f, ss = 0.f;
      #pragma unroll
      for (int k = 0; k < 16; k++) { const float2 v = part[tid][k]; s += v.x; ss += v.y; }
      const float mean = s * (1.0f / 256.0f);
      const float var  = ss * (1.0f / 256.0f) - mean * mean;
      stats[tid][0] = mean;
      stats[tid][1] = rsqrtf(var + 1e-5f);
    }
    __syncthreads();
    if (p == 0) {
      #pragma unroll
      for (int i = 0; i < 2; i++)
        #pragma unroll
        for (int r = 0; r < 4; r++) {
          const int row = rbase + i * 16 + fq * 4 + r;
          const float mean = stats[row][0], rstd = stats[row][1];
          #pragma unroll
          for (int j = 0; j < 4; j++) {
            const int col = wc * 64 + j * 16 + fr;
            const float y = fmaxf((acc[i][j][r] - mean) * rstd * vw[j] + vl[j], 0.f);
            hprev[i][j][r] = y;
            const float yp = dpp_x1(y);
            if ((fr & 1) == 0)
              *(u32*)&As[row * APAD + col] = pk_bf16(y, yp);
          }
        }
      __syncthreads();
    } else {
      #pragma unroll
      for (int i = 0; i < 2; i++)
        #pragma unroll
        for (int r = 0; r < 4; r++) {
          const int row = rbase + i * 16 + fq * 4 + r;
          const float mean = stats[row][0], rstd = stats[row][1];
          #pragma unroll
          for (int j = 0; j < 4; j++) {
            const int col = wc * 64 + j * 16 + fr;
            const float y = fmaxf((acc[i][j][r] - mean) * rstd * vw[j] + vl[j], 0.f);
            out[(size_t)(m0 + row) * 256 + col] = y;
          }
        }
    }
  }
}

// ---------------------------------------------------------------------------
extern "C" void kernel_launch(void* const* d_in, const int* in_sizes, int n_in,
                              void* d_out, int out_size, void* d_ws, size_t ws_size,
                              hipStream_t stream)
{
  (void)in_sizes; (void)n_in; (void)out_size; (void)ws_size;
  const float* x     = (const float*)d_in[0];
  const float* fc0_w = (const float*)d_in[2];
  const float* fc0_b = (const float*)d_in[3];
  const float* ln0_w = (const float*)d_in[4];
  const float* ln0_b = (const float*)d_in[5];
  const float* ln1_w = (const float*)d_in[6];
  const float* ln1_b = (const float*)d_in[7];
  const float* ln2_w = (const float*)d_in[8];
  const float* ln2_b = (const float*)d_in[9];
  const float* wv0_w = (const float*)d_in[14];
  const float* wv0_b = (const float*)d_in[15];
  const float* wv1_w = (const float*)d_in[20];
  const float* wv1_b = (const float*)d_in[21];

  // workspace (~274 KB)
  char* ws = (char*)d_ws;
  u16*   w2_0 = (u16*)(ws);                  // 128 KB (K-major)
  u16*   w2_1 = (u16*)(ws + 131072ull);      // 128 KB
  u16*   w0T  = (u16*)(ws + 262144ull);      // 8 KB
  float* bvm0 = (float*)(ws + 270336ull);
  float* bvm1 = (float*)(ws + 271360ull);

  k_prep<<<33, 256, 0, stream>>>(fc0_w, wv0_w, wv0_b, wv1_w, wv1_b,
                                 w0T, w2_0, bvm0, w2_1, bvm1);
  k_mega<<<512, 512, 0, stream>>>(x, w0T, fc0_b, ln0_w, ln0_b,
                                  w2_0, bvm0, ln1_w, ln1_b,
                                  w2_1, bvm1, ln2_w, ln2_b,
                                  (float*)d_out);
}

// Round 17
// 35.188 us; speedup vs baseline: 1.3887x; 1.3887x over previous
//
#include <hip/hip_runtime.h>
#include <stdint.h>

// TransConv fused form, round 17 = byte-exact revert to round 14 (best: 35.4us).
// r15/r16 post-mortem: both epilogue-diet variants (cvt_pk + hprev-in-regs)
// regressed via hprev SPILLING to scratch (VGPR_Count pinned at 64; +54MB
// write / +22MB fetch scratch traffic). Reverting to the proven best.
// Validated algebra (r2-r16, absmax <= 0.0625):
//   h <- relu(LN((h @ Wv_mean + bvm + h)/2)),  Wv_mean = head-mean of Wv,
//   fc0: h0 = relu(LN(x @ fc0_w + fc0_b)).

typedef unsigned short u16;
typedef unsigned int u32;
typedef __attribute__((ext_vector_type(8))) short bf16x8;
typedef __attribute__((ext_vector_type(8))) unsigned short u16x8;
typedef __attribute__((ext_vector_type(4))) float f32x4;

#define APAD 264   // As row stride (u16): 528B rows -> uniform 8-bank-group spread

static __device__ __forceinline__ float bf2f(u16 u) {
  union { u32 i; float f; } c; c.i = ((u32)u) << 16; return c.f;
}
static __device__ __forceinline__ u16 f2bf(float f) {
  union { float ff; u32 i; } c; c.ff = f;
  u32 x = c.i;
  x += 0x7fffu + ((x >> 16) & 1u);   // RNE
  return (u16)(x >> 16);
}
static __device__ __forceinline__ bf16x8 as_bf(u16x8 v) {
  union { u16x8 a; bf16x8 b; } c; c.a = v; return c.b;
}
// quad_perm DPP lane exchanges (pure VALU, no LDS/lgkm):
static __device__ __forceinline__ float dpp_x1(float v) {   // lane ^ 1
  return __int_as_float(__builtin_amdgcn_mov_dpp(__float_as_int(v), 0xB1, 0xF, 0xF, true));
}
static __device__ __forceinline__ float dpp_x2(float v) {   // lane ^ 2
  return __int_as_float(__builtin_amdgcn_mov_dpp(__float_as_int(v), 0x4E, 0xF, 0xF, true));
}
static __device__ __forceinline__ u32 dpp_x1u(u32 v) {
  return (u32)__builtin_amdgcn_mov_dpp((int)v, 0xB1, 0xF, 0xF, true);
}

// ---------------------------------------------------------------------------
// Prep (unchanged since r5). grid 33 x 256.
//  bid 0..31 : W2{L}[kt][d][q][e] = bf16(mean_h wv{L}[kt*32+q*8+e][h*256+d])
//  bid 32    : w0T[d][k] = bf16(fc0_w[k][d]);  bvm{L}[d] = mean_h bv{L}
// ---------------------------------------------------------------------------
__global__ __launch_bounds__(256) void k_prep(
    const float* __restrict__ fc0_w,
    const float* __restrict__ wv0, const float* __restrict__ bv0,
    const float* __restrict__ wv1, const float* __restrict__ bv1,
    u16* __restrict__ w0T,
    u16* __restrict__ w2_0, float* __restrict__ bvm0,
    u16* __restrict__ w2_1, float* __restrict__ bvm1)
{
  const int bid = blockIdx.x, tid = threadIdx.x;
  if (bid < 32) {
    __shared__ u16 t[64][72];
    const int L  = bid >> 4;
    const int ti = (bid >> 2) & 3;
    const int tj = bid & 3;
    const float* wv = L ? wv1 : wv0;
    u16* W2 = L ? w2_1 : w2_0;
    const int cl = tid >> 2, dq = tid & 3;
    #pragma unroll
    for (int e = 0; e < 16; e++) {
      const int dl = dq * 16 + e;
      const float* p = wv + (size_t)(ti * 64 + cl) * 1024 + tj * 64 + dl;
      t[cl][dl] = f2bf(0.25f * (p[0] + p[256] + p[512] + p[768]));
    }
    __syncthreads();
    const int dl = tid >> 2, cq = tid & 3;
    u16x8 v0, v1;
    #pragma unroll
    for (int e = 0; e < 8; e++) { v0[e] = t[cq * 16 + e][dl]; v1[e] = t[cq * 16 + 8 + e][dl]; }
    const int kt = ti * 2 + (cq >> 1);
    const int q0 = (cq & 1) * 2;
    const int d  = tj * 64 + dl;
    u16* dst = W2 + kt * 8192 + d * 32 + q0 * 8;
    *(u16x8*)dst = v0;
    *(u16x8*)(dst + 8) = v1;
  } else {
    const int d = tid;
    u16x8 r0, r1;
    #pragma unroll
    for (int k = 0; k < 8; k++) {
      r0[k] = f2bf(fc0_w[k * 256 + d]);
      r1[k] = f2bf(fc0_w[(k + 8) * 256 + d]);
    }
    *(u16x8*)(w0T + d * 16) = r0;
    *(u16x8*)(w0T + d * 16 + 8) = r1;
    float t0 = 0.f, t1 = 0.f;
    #pragma unroll
    for (int h = 0; h < 4; h++) { t0 += bv0[h * 256 + d]; t1 += bv1[h * 256 + d]; }
    bvm0[d] = 0.25f * t0;
    bvm1[d] = 0.25f * t1;
  }
}

// ---------------------------------------------------------------------------
// Mega kernel: 512 blocks x 512 threads (8 waves: 2 row-groups x 4 col-
// stripes), 64 rows/block, 2 blocks/CU. Weight chunks K=32 (16KB) dbuf,
// XOR-swizzled. Epilogue: quad-DPP + LDS float2 partials.
// C/D map (HW-verified m89/m91): row = rbase + i*16 + fq*4 + r,
//                                col = wc*64 + j*16 + fr.
// Bs swizzle: slot' = slot ^ ((row>>1)&3); read kcB = (fq^((fr>>1)&3))<<3
// (store/read permutations cancel; verified correct in r13/r14).
// ---------------------------------------------------------------------------
__global__ __launch_bounds__(512, 4) void k_mega(
    const float* __restrict__ x,
    const u16* __restrict__ w0T, const float* __restrict__ fc0_b,
    const float* __restrict__ ln0w, const float* __restrict__ ln0b,
    const u16* __restrict__ w2_0, const float* __restrict__ bvm0,
    const float* __restrict__ ln1w, const float* __restrict__ ln1b,
    const u16* __restrict__ w2_1, const float* __restrict__ bvm1,
    const float* __restrict__ ln2w, const float* __restrict__ ln2b,
    float* __restrict__ out)
{
  __shared__ u16 As[64 * APAD];        // 33.8 KB: the h tile
  __shared__ u16 Bs[2][8192];          // 32 KB: K=32 weight chunk double-buffer
  __shared__ float2 part[64][17];      // 8.7 KB
  __shared__ float stats[64][2];       // 0.5 KB            -> 75.8 KB total

  const int tid  = threadIdx.x;
  const int lane = tid & 63;
  const int w    = tid >> 6;        // 0..7
  const int wr   = w >> 2;          // row-group (0..1), 32 rows each
  const int wc   = w & 3;           // col-stripe (0..3), 64 cols each
  const int fr   = lane & 15;
  const int fq   = lane >> 4;
  const int kc   = fq << 3;
  const int kcB  = (fq ^ ((fr >> 1) & 3)) << 3;   // swizzled B chunk offset
  const int m0   = blockIdx.x * 64;
  const int rbase = wr * 32;
  const int qidx = wc * 4 + (fr >> 2);            // partial slot
  // swizzled staging dest (logical elem tid*8: row=tid>>2, slot=tid&3)
  const int swdst = ((tid >> 2) << 5) | (((tid & 3) ^ ((tid >> 3) & 3)) << 3);

  f32x4 acc[2][4];
  #pragma unroll
  for (int i = 0; i < 2; i++)
    #pragma unroll
    for (int j = 0; j < 4; j++)
      acc[i][j] = f32x4{0.f, 0.f, 0.f, 0.f};

  // ---- Phase 0 MFMA: fc0, K=16 zero-padded to 32, operands from global ----
  {
    bf16x8 af[2], bg[4];
    if (kc < 16) {
      #pragma unroll
      for (int i = 0; i < 2; i++) {
        const float* xp = x + (size_t)(m0 + rbase + i * 16 + fr) * 16 + kc;
        const f32x4 lo = *(const f32x4*)xp;
        const f32x4 hi = *(const f32x4*)(xp + 4);
        u16x8 v;
        #pragma unroll
        for (int e = 0; e < 4; e++) { v[e] = f2bf(lo[e]); v[4 + e] = f2bf(hi[e]); }
        af[i] = as_bf(v);
      }
      #pragma unroll
      for (int j = 0; j < 4; j++)
        bg[j] = as_bf(*(const u16x8*)(w0T + (wc * 64 + j * 16 + fr) * 16 + kc));
    } else {
      const u16x8 z = {0,0,0,0,0,0,0,0};
      #pragma unroll
      for (int i = 0; i < 2; i++) af[i] = as_bf(z);
      #pragma unroll
      for (int j = 0; j < 4; j++) bg[j] = as_bf(z);
    }
    #pragma unroll
    for (int i = 0; i < 2; i++)
      #pragma unroll
      for (int j = 0; j < 4; j++)
        acc[i][j] = __builtin_amdgcn_mfma_f32_16x16x32_bf16(af[i], bg[j], acc[i][j], 0, 0, 0);
  }

  // ---- Phase 0 epilogue: +fc0_b, row-LN(ln0), relu -> As ----
  {
    float vb[4], vw[4], vl[4];
    #pragma unroll
    for (int j = 0; j < 4; j++) {
      const int c = wc * 64 + j * 16 + fr;
      vb[j] = fc0_b[c]; vw[j] = ln0w[c]; vl[j] = ln0b[c];
    }
    #pragma unroll
    for (int i = 0; i < 2; i++)
      #pragma unroll
      for (int r = 0; r < 4; r++) {
        const int row = rbase + i * 16 + fq * 4 + r;
        float s = 0.f, ss = 0.f;
        #pragma unroll
        for (int j = 0; j < 4; j++) {
          const float xv = acc[i][j][r] + vb[j];
          acc[i][j][r] = xv;
          s += xv; ss += xv * xv;
        }
        s += dpp_x1(s);  ss += dpp_x1(ss);
        s += dpp_x2(s);  ss += dpp_x2(ss);
        if ((fr & 3) == 0) part[row][qidx] = float2{s, ss};
      }
    __syncthreads();
    if (tid < 64) {
      float s = 0.f, ss = 0.f;
      #pragma unroll
      for (int k = 0; k < 16; k++) { const float2 v = part[tid][k]; s += v.x; ss += v.y; }
      const float mean = s * (1.0f / 256.0f);
      const float var  = ss * (1.0f / 256.0f) - mean * mean;
      stats[tid][0] = mean;
      stats[tid][1] = rsqrtf(var + 1e-5f);
    }
    __syncthreads();
    #pragma unroll
    for (int i = 0; i < 2; i++)
      #pragma unroll
      for (int r = 0; r < 4; r++) {
        const int row = rbase + i * 16 + fq * 4 + r;
        const float mean = stats[row][0], rstd = stats[row][1];
        #pragma unroll
        for (int j = 0; j < 4; j++) {
          const int col = wc * 64 + j * 16 + fr;
          const float y = fmaxf((acc[i][j][r] - mean) * rstd * vw[j] + vl[j], 0.f);
          const u32 self = f2bf(y);
          const u32 peer = dpp_x1u(self);
          if ((fr & 1) == 0)
            *(u32*)&As[row * APAD + col] = self | (peer << 16);
        }
      }
    __syncthreads();
  }

  // ---- Phases 1 & 2: h <- relu(LN((h @ W + bvm + h)/2)) ----
  #pragma unroll 1
  for (int p = 0; p < 2; p++) {
    const u16* W2 = p ? w2_1 : w2_0;
    const float* bvp = p ? bvm1 : bvm0;
    const float* lw  = p ? ln2w : ln1w;
    const float* lb  = p ? ln2b : ln1b;

    #pragma unroll
    for (int i = 0; i < 2; i++)
      #pragma unroll
      for (int j = 0; j < 4; j++)
        acc[i][j] = f32x4{0.f, 0.f, 0.f, 0.f};

    // LDS-staged K-loop: 8 chunks of K=32 (8192 u16), dbuf, swizzled
    u16x8 s0 = *(const u16x8*)(W2 + tid * 8);
    u16x8 s1 = *(const u16x8*)(W2 + 4096 + tid * 8);
    *(u16x8*)(&Bs[0][swdst]) = s0;
    *(u16x8*)(&Bs[0][4096 + swdst]) = s1;

    #pragma unroll
    for (int c = 0; c < 8; c++) {
      if (c < 7) {                       // issue next chunk's global loads
        s0 = *(const u16x8*)(W2 + (c + 1) * 8192 + tid * 8);
        s1 = *(const u16x8*)(W2 + (c + 1) * 8192 + 4096 + tid * 8);
      }
      __syncthreads();                   // buf[c&1] writes visible
      const u16* bbase = &Bs[c & 1][0];
      bf16x8 a[2], b[4];
      #pragma unroll
      for (int i = 0; i < 2; i++)
        a[i] = *(const bf16x8*)(As + (rbase + i * 16 + fr) * APAD + c * 32 + kc);
      #pragma unroll
      for (int j = 0; j < 4; j++)
        b[j] = *(const bf16x8*)(bbase + (wc * 64 + j * 16 + fr) * 32 + kcB);
      #pragma unroll
      for (int i = 0; i < 2; i++)
        #pragma unroll
        for (int j = 0; j < 4; j++)
          acc[i][j] = __builtin_amdgcn_mfma_f32_16x16x32_bf16(a[i], b[j], acc[i][j], 0, 0, 0);
      if (c < 7) {                       // write next chunk into other buffer
        *(u16x8*)(&Bs[(c + 1) & 1][swdst]) = s0;
        *(u16x8*)(&Bs[(c + 1) & 1][4096 + swdst]) = s1;
      }
    }

    // epilogue: xv = (C + bvm + h_prev)/2, row-LN via DPP+LDS partials
    float vb[4], vw[4], vl[4];
    #pragma unroll
    for (int j = 0; j < 4; j++) {
      const int c = wc * 64 + j * 16 + fr;
      vb[j] = bvp[c]; vw[j] = lw[c]; vl[j] = lb[c];
    }
    #pragma unroll
    for (int i = 0; i < 2; i++)
      #pragma unroll
      for (int r = 0; r < 4; r++) {
        const int row = rbase + i * 16 + fq * 4 + r;
        float s = 0.f, ss = 0.f;
        #pragma unroll
        for (int j = 0; j < 4; j++) {
          const int col = wc * 64 + j * 16 + fr;
          const float prev = bf2f(As[row * APAD + col]);
          const float xv = (acc[i][j][r] + vb[j] + prev) * 0.5f;
          acc[i][j][r] = xv;
          s += xv; ss += xv * xv;
        }
        s += dpp_x1(s);  ss += dpp_x1(ss);
        s += dpp_x2(s);  ss += dpp_x2(ss);
        if ((fr & 3) == 0) part[row][qidx] = float2{s, ss};
      }
    __syncthreads();
    if (tid < 64) {
      float s = 0.f, ss = 0.f;
      #pragma unroll
      for (int k = 0; k < 16; k++) { const float2 v = part[tid][k]; s += v.x; ss += v.y; }
      const float mean = s * (1.0f / 256.0f);
      const float var  = ss * (1.0f / 256.0f) - mean * mean;
      stats[tid][0] = mean;
      stats[tid][1] = rsqrtf(var + 1e-5f);
    }
    __syncthreads();
    if (p == 0) {
      #pragma unroll
      for (int i = 0; i < 2; i++)
        #pragma unroll
        for (int r = 0; r < 4; r++) {
          const int row = rbase + i * 16 + fq * 4 + r;
          const float mean = stats[row][0], rstd = stats[row][1];
          #pragma unroll
          for (int j = 0; j < 4; j++) {
            const int col = wc * 64 + j * 16 + fr;
            const float y = fmaxf((acc[i][j][r] - mean) * rstd * vw[j] + vl[j], 0.f);
            const u32 self = f2bf(y);
            const u32 peer = dpp_x1u(self);
            if ((fr & 1) == 0)
              *(u32*)&As[row * APAD + col] = self | (peer << 16);
          }
        }
      __syncthreads();
    } else {
      #pragma unroll
      for (int i = 0; i < 2; i++)
        #pragma unroll
        for (int r = 0; r < 4; r++) {
          const int row = rbase + i * 16 + fq * 4 + r;
          const float mean = stats[row][0], rstd = stats[row][1];
          #pragma unroll
          for (int j = 0; j < 4; j++) {
            const int col = wc * 64 + j * 16 + fr;
            const float y = fmaxf((acc[i][j][r] - mean) * rstd * vw[j] + vl[j], 0.f);
            out[(size_t)(m0 + row) * 256 + col] = y;
          }
        }
    }
  }
}

// ---------------------------------------------------------------------------
extern "C" void kernel_launch(void* const* d_in, const int* in_sizes, int n_in,
                              void* d_out, int out_size, void* d_ws, size_t ws_size,
                              hipStream_t stream)
{
  (void)in_sizes; (void)n_in; (void)out_size; (void)ws_size;
  const float* x     = (const float*)d_in[0];
  const float* fc0_w = (const float*)d_in[2];
  const float* fc0_b = (const float*)d_in[3];
  const float* ln0_w = (const float*)d_in[4];
  const float* ln0_b = (const float*)d_in[5];
  const float* ln1_w = (const float*)d_in[6];
  const float* ln1_b = (const float*)d_in[7];
  const float* ln2_w = (const float*)d_in[8];
  const float* ln2_b = (const float*)d_in[9];
  const float* wv0_w = (const float*)d_in[14];
  const float* wv0_b = (const float*)d_in[15];
  const float* wv1_w = (const float*)d_in[20];
  const float* wv1_b = (const float*)d_in[21];

  // workspace (~274 KB)
  char* ws = (char*)d_ws;
  u16*   w2_0 = (u16*)(ws);                  // 128 KB (K-major)
  u16*   w2_1 = (u16*)(ws + 131072ull);      // 128 KB
  u16*   w0T  = (u16*)(ws + 262144ull);      // 8 KB
  float* bvm0 = (float*)(ws + 270336ull);
  float* bvm1 = (float*)(ws + 271360ull);

  k_prep<<<33, 256, 0, stream>>>(fc0_w, wv0_w, wv0_b, wv1_w, wv1_b,
                                 w0T, w2_0, bvm0, w2_1, bvm1);
  k_mega<<<512, 512, 0, stream>>>(x, w0T, fc0_b, ln0_w, ln0_b,
                                  w2_0, bvm0, ln1_w, ln1_b,
                                  w2_1, bvm1, ln2_w, ln2_b,
                                  (float*)d_out);
}